// Round 10
// baseline (227.288 us; speedup 1.0000x reference)
//
#include <hip/hip_runtime.h>
#include <math.h>

typedef unsigned short u16;
typedef __attribute__((ext_vector_type(8))) short short8;
typedef __attribute__((ext_vector_type(4))) float floatx4;

#define LDS_P 72  // padded LDS row stride for 64-wide tiles

__device__ __forceinline__ float bf2f(u16 u) {
  union { unsigned int i; float f; } v; v.i = ((unsigned int)u) << 16; return v.f;
}
__device__ __forceinline__ u16 f2bf(float f) {
  union { float f; unsigned int i; } v; v.f = f;
  unsigned int x = v.i;
  return (u16)((x + 0x7FFFu + ((x >> 16) & 1u)) >> 16);
}

// ---- core 64x64 tile loop, LDS double-buffered, one barrier per K-slab -----
// As/Bs are 2 buffers of 64*LDS_P u16 each (As[0|4608...], Bs likewise)
__device__ __forceinline__ void mfma_loop(const u16* __restrict__ A, int lda,
                                          const u16* __restrict__ Bt, int ldb,
                                          int K, u16* As, u16* Bs,
                                          floatx4 acc[2][2], int tid) {
  int lane = tid & 63;
  int wm = ((tid >> 6) & 1) << 5, wn = ((tid >> 6) >> 1) << 5;
  int lr = lane & 15, lq8 = (lane >> 4) << 3;
  int r0 = tid >> 3, c8 = (tid & 7) << 3;

  const u16* pA0 = A + (long long)r0 * lda + c8;
  const u16* pA1 = A + (long long)(r0 + 32) * lda + c8;
  const u16* pB0 = Bt + (long long)r0 * ldb + c8;
  const u16* pB1 = Bt + (long long)(r0 + 32) * ldb + c8;
  float4 a0 = *reinterpret_cast<const float4*>(pA0);
  float4 a1 = *reinterpret_cast<const float4*>(pA1);
  float4 b0 = *reinterpret_cast<const float4*>(pB0);
  float4 b1 = *reinterpret_cast<const float4*>(pB1);
  *reinterpret_cast<float4*>(As + r0 * LDS_P + c8) = a0;
  *reinterpret_cast<float4*>(As + (r0 + 32) * LDS_P + c8) = a1;
  *reinterpret_cast<float4*>(Bs + r0 * LDS_P + c8) = b0;
  *reinterpret_cast<float4*>(Bs + (r0 + 32) * LDS_P + c8) = b1;
  __syncthreads();

  int nslab = K >> 6;
  for (int s = 0; s < nslab; ++s) {
    const u16* Ac = As + (s & 1) * 4608;
    const u16* Bc = Bs + (s & 1) * 4608;
    if (s + 1 < nslab) {
      int off = (s + 1) << 6;
      a0 = *reinterpret_cast<const float4*>(pA0 + off);
      a1 = *reinterpret_cast<const float4*>(pA1 + off);
      b0 = *reinterpret_cast<const float4*>(pB0 + off);
      b1 = *reinterpret_cast<const float4*>(pB1 + off);
    }
#pragma unroll
    for (int kc = 0; kc < 64; kc += 32) {
      short8 fa0 = *reinterpret_cast<const short8*>(Ac + (wm + lr) * LDS_P + kc + lq8);
      short8 fa1 = *reinterpret_cast<const short8*>(Ac + (wm + 16 + lr) * LDS_P + kc + lq8);
      short8 fb0 = *reinterpret_cast<const short8*>(Bc + (wn + lr) * LDS_P + kc + lq8);
      short8 fb1 = *reinterpret_cast<const short8*>(Bc + (wn + 16 + lr) * LDS_P + kc + lq8);
      acc[0][0] = __builtin_amdgcn_mfma_f32_16x16x32_bf16(fa0, fb0, acc[0][0], 0, 0, 0);
      acc[0][1] = __builtin_amdgcn_mfma_f32_16x16x32_bf16(fa0, fb1, acc[0][1], 0, 0, 0);
      acc[1][0] = __builtin_amdgcn_mfma_f32_16x16x32_bf16(fa1, fb0, acc[1][0], 0, 0, 0);
      acc[1][1] = __builtin_amdgcn_mfma_f32_16x16x32_bf16(fa1, fb1, acc[1][1], 0, 0, 0);
    }
    if (s + 1 < nslab) {
      u16* An = As + ((s + 1) & 1) * 4608;
      u16* Bn = Bs + ((s + 1) & 1) * 4608;
      *reinterpret_cast<float4*>(An + r0 * LDS_P + c8) = a0;
      *reinterpret_cast<float4*>(An + (r0 + 32) * LDS_P + c8) = a1;
      *reinterpret_cast<float4*>(Bn + r0 * LDS_P + c8) = b0;
      *reinterpret_cast<float4*>(Bn + (r0 + 32) * LDS_P + c8) = b1;
    }
    __syncthreads();
  }
}

#define EPI_SETUP                                                     \
  int lane = threadIdx.x & 63;                                        \
  int wm = ((threadIdx.x >> 6) & 1) << 5,                             \
      wn = ((threadIdx.x >> 6) >> 1) << 5;                            \
  int lr = lane & 15, lq4 = (lane >> 4) << 2;

// ---- q+k projections in one launch (z=0:Q, z=1:K) --------------------------
__global__ __launch_bounds__(256) void proj2_k(
    const u16* __restrict__ A, const u16* __restrict__ WQT,
    const u16* __restrict__ WKT, const float* __restrict__ b_Q,
    const float* __restrict__ b_K, u16* __restrict__ qbf,
    u16* __restrict__ kbf) {
  __shared__ u16 As[2 * 64 * LDS_P], Bs[2 * 64 * LDS_P];
  int z = blockIdx.z;
  int m0 = blockIdx.y << 6, n0 = blockIdx.x << 6;
  int K = z ? 256 : 512, ldb = z ? 256 : 512;
  const u16* Bt = z ? WKT : WQT;
  const float* bias = z ? b_K : b_Q;
  u16* C = z ? kbf : qbf;
  floatx4 acc[2][2] = {};
  mfma_loop(A + (long long)m0 * 512, 512, Bt + (long long)n0 * ldb, ldb, K, As, Bs,
            acc, threadIdx.x);
  EPI_SETUP
#pragma unroll
  for (int ti = 0; ti < 2; ++ti)
#pragma unroll
    for (int tj = 0; tj < 2; ++tj)
#pragma unroll
      for (int r = 0; r < 4; ++r) {
        int row = m0 + wm + ti * 16 + lq4 + r;
        int col = n0 + wn + tj * 16 + lr;
        C[(long long)row * 256 + col] = f2bf(acc[ti][tj][r] + bias[col]);
      }
}

// ---- scores, all 16 z-slices (z = h*4+b), bf16 output ----------------------
__global__ __launch_bounds__(256) void mscore_k(
    const u16* __restrict__ q, const u16* __restrict__ kb,
    u16* __restrict__ sc) {
  __shared__ u16 As[2 * 64 * LDS_P], Bs[2 * 64 * LDS_P];
  int z = blockIdx.z;
  int b = z & 3, h = z >> 2;
  int m0 = blockIdx.y << 6, n0 = blockIdx.x << 6;
  const u16* Ab = q + b * 262144 + h * 64;
  const u16* Bb = kb + b * 262144 + h * 64;
  floatx4 acc[2][2] = {};
  mfma_loop(Ab + (long long)m0 * 256, 256, Bb + (long long)n0 * 256, 256, 64, As, Bs,
            acc, threadIdx.x);
  u16* Cb = sc + ((long long)z << 20);
  EPI_SETUP
#pragma unroll
  for (int ti = 0; ti < 2; ++ti)
#pragma unroll
    for (int tj = 0; tj < 2; ++tj)
#pragma unroll
      for (int r = 0; r < 4; ++r) {
        int row = m0 + wm + ti * 16 + lq4 + r;
        int col = n0 + wn + tj * 16 + lr;
        Cb[(long long)row * 1024 + col] = f2bf(acc[ti][tj][r]);
      }
}

// ---- wave-level reductions (no barriers) -----------------------------------
__device__ __forceinline__ float wred_sum(float v) {
#pragma unroll
  for (int m = 32; m > 0; m >>= 1) v += __shfl_xor(v, m, 64);
  return v;
}
__device__ __forceinline__ void wred_sum2(float& a, float& b) {
#pragma unroll
  for (int m = 32; m > 0; m >>= 1) {
    float ta = __shfl_xor(a, m, 64);
    float tb = __shfl_xor(b, m, 64);
    a += ta; b += tb;
  }
}
__device__ __forceinline__ float wred_max(float v) {
#pragma unroll
  for (int m = 32; m > 0; m >>= 1) v = fmaxf(v, __shfl_xor(v, m, 64));
  return v;
}

// ---- z-score attention: one wave per row, all 4 heads ----------------------
__global__ __launch_bounds__(256) void zscore_w(
    const u16* __restrict__ sc, const int* __restrict__ adj,
    const int* __restrict__ mask, u16* __restrict__ wout,
    float* __restrict__ denh) {
  int wv = threadIdx.x >> 6, lane = threadIdx.x & 63;
  int row = (blockIdx.x << 2) + wv;
  int b = row >> 10, n = row & 1023;
  int e0 = lane << 4;
  const int* arow = adj + ((long long)row << 10) + e0;
  const int* mrow = mask + (b << 10) + e0;

  unsigned int vbits = 0, abits = 0;
#pragma unroll
  for (int q = 0; q < 4; ++q) {
    int4 a4 = *reinterpret_cast<const int4*>(arow + (q << 2));
    int4 m4 = *reinterpret_cast<const int4*>(mrow + (q << 2));
    vbits |= (unsigned)(m4.x == 0) << (q * 4);
    vbits |= (unsigned)(m4.y == 0) << (q * 4 + 1);
    vbits |= (unsigned)(m4.z == 0) << (q * 4 + 2);
    vbits |= (unsigned)(m4.w == 0) << (q * 4 + 3);
    abits |= (unsigned)(a4.x != 0) << (q * 4);
    abits |= (unsigned)(a4.y != 0) << (q * 4 + 1);
    abits |= (unsigned)(a4.z != 0) << (q * 4 + 2);
    abits |= (unsigned)(a4.w != 0) << (q * 4 + 3);
  }
  float cnt = wred_sum((float)__popc(vbits));
  float cnteff = cnt + 0.0001f;

  for (int h = 0; h < 4; ++h) {
    int z = (h << 2) + b;
    const u16* srow = sc + ((long long)z << 20) + ((long long)n << 10) + e0;
    float s[16];
#pragma unroll
    for (int q = 0; q < 2; ++q) {
      uint4 u = *reinterpret_cast<const uint4*>(srow + (q << 3));
      unsigned int uu[4] = {u.x, u.y, u.z, u.w};
#pragma unroll
      for (int t = 0; t < 4; ++t) {
        union { unsigned int i; float f; } lo, hi;
        lo.i = uu[t] << 16;
        hi.i = uu[t] & 0xffff0000u;
        s[q * 8 + t * 2] = lo.f;
        s[q * 8 + t * 2 + 1] = hi.f;
      }
    }
    float suml = 0.f, sql = 0.f;
#pragma unroll
    for (int u = 0; u < 16; ++u)
      if ((vbits >> u) & 1) { suml += s[u]; sql += s[u] * s[u]; }
    wred_sum2(suml, sql);
    float mean = suml / cnteff;
    float sdata = sql - 2.f * mean * suml + cnt * mean * mean;
    float stdv = sqrtf(fmaxf(sdata, 0.f) / cnteff + 1e-10f);
    float inv = 1.f / (stdv + 0.0001f);

    float maxl = -1e9f;
#pragma unroll
    for (int u = 0; u < 16; ++u) {
      float zz = (s[u] - mean) * inv;
      int vv = (vbits >> u) & 1;
      zz = vv ? zz : 0.f;
      s[u] = zz;
      if (vv && zz >= 0.f) maxl = fmaxf(maxl, zz);
    }
    float rowmax = wred_max(maxl);

    float e[16], el = 0.f;
#pragma unroll
    for (int u = 0; u < 16; ++u) {
      int vv = (vbits >> u) & 1, aa = (abits >> u) & 1;
      float ev = (vv && aa && (s[u] >= 0.f)) ? expf(s[u] - rowmax) : 0.f;
      e[u] = ev + 1e-10f;
      el += e[u];
    }
    float esum = wred_sum(el);
    float rinv = 1.f / esum;

    float wl = 0.f;
    unsigned int wo[8];
#pragma unroll
    for (int u = 0; u < 16; u += 2) {
      int s0 = ((vbits >> u) & 1) && ((abits >> u) & 1) && (s[u] >= 0.f);
      int s1 = ((vbits >> (u + 1)) & 1) && ((abits >> (u + 1)) & 1) && (s[u + 1] >= 0.f);
      float w0 = s0 ? e[u] * rinv : 0.f;
      float w1 = s1 ? e[u + 1] * rinv : 0.f;
      wl += w0 + w1;
      wo[u >> 1] = (unsigned)f2bf(w0) | ((unsigned)f2bf(w1) << 16);
    }
    float wsum = wred_sum(wl);

    u16* orow = wout + ((size_t)z << 20) + ((size_t)n << 10) + e0;
    reinterpret_cast<uint4*>(orow)[0] = make_uint4(wo[0], wo[1], wo[2], wo[3]);
    reinterpret_cast<uint4*>(orow)[1] = make_uint4(wo[4], wo[5], wo[6], wo[7]);
    if (lane == 0) denh[(z << 10) + n] = wsum + 1.0f;
  }
}

// ---- fused GCN layer: 64-row tiles, LDS double-buffered both stages --------
// T(64x256) = wght@srcT^T + addsrc -> LDS -> relu((T@Wg^T+2b)/den) -> fin (+obT)
__global__ __launch_bounds__(256) void gcn_k(
    const u16* __restrict__ wght, const u16* __restrict__ srcT, int zmaskB,
    const u16* __restrict__ addsrc, int ldadd, long long sAdd, int hmul,
    const u16* __restrict__ WgT_all, const float* __restrict__ bg_all,
    const float* __restrict__ den, int l,
    u16* __restrict__ obT, u16* __restrict__ fin) {
  __shared__ u16 lds[53760];  // 107.5 KB (1 block/CU by grid anyway)
  // stage 1: As0[0,4608) As1[4608,9216) Bs0[9216,27648) Bs1[27648,46080)
  // stage 2: Ts[0,16896) Ws0[16896,35328) Ws1[35328,53760)
  u16* As0 = lds;
  u16* As1 = lds + 4608;
  u16* Bs0 = lds + 9216;
  u16* Bs1 = lds + 27648;
  u16* Ts = lds;
  u16* Ws0 = lds + 16896;
  u16* Ws1 = lds + 35328;
  int tid = threadIdx.x;
  int m0 = blockIdx.x << 6;
  int z = blockIdx.y;
  int lane = tid & 63, w = tid >> 6;
  int lr = lane & 15, lq8 = (lane >> 4) << 3, lq4 = (lane >> 4) << 2;

  const u16* Aw = wght + ((long long)z << 20) + (long long)m0 * 1024;
  const u16* Bt = srcT + (long long)(z & zmaskB) * 262144;
  const u16* addb = addsrc + (long long)(z & 3) * sAdd + (z >> 2) * hmul;
  int idx2 = (z >> 2) * 2 + l;
  const u16* Wg = WgT_all + (long long)idx2 * 65536;

  floatx4 acc[4][4] = {};
  float4 pa[2], pb[8];
  int rowA[2], colA[2], rowB[8], colB[8];
#pragma unroll
  for (int j = 0; j < 2; ++j) {
    int id = tid + (j << 8);
    rowA[j] = id >> 3; colA[j] = (id & 7) << 3;
  }
#pragma unroll
  for (int j = 0; j < 8; ++j) {
    int id = tid + (j << 8);
    rowB[j] = id >> 3; colB[j] = (id & 7) << 3;
  }

  // prologue: slab 0 -> buf0
#pragma unroll
  for (int j = 0; j < 2; ++j)
    pa[j] = *reinterpret_cast<const float4*>(Aw + (long long)rowA[j] * 1024 + colA[j]);
#pragma unroll
  for (int j = 0; j < 8; ++j)
    pb[j] = *reinterpret_cast<const float4*>(Bt + (long long)rowB[j] * 1024 + colB[j]);
#pragma unroll
  for (int j = 0; j < 2; ++j)
    *reinterpret_cast<float4*>(As0 + rowA[j] * 72 + colA[j]) = pa[j];
#pragma unroll
  for (int j = 0; j < 8; ++j)
    *reinterpret_cast<float4*>(Bs0 + rowB[j] * 72 + colB[j]) = pb[j];
  __syncthreads();

  // ---- stage 1: K=1024, 16 slabs, single barrier each ----
  for (int s = 0; s < 16; ++s) {
    const u16* Ac = (s & 1) ? As1 : As0;
    const u16* Bc = (s & 1) ? Bs1 : Bs0;
    if (s < 15) {
      int off = (s + 1) << 6;
#pragma unroll
      for (int j = 0; j < 2; ++j)
        pa[j] = *reinterpret_cast<const float4*>(Aw + (long long)rowA[j] * 1024 + off + colA[j]);
#pragma unroll
      for (int j = 0; j < 8; ++j)
        pb[j] = *reinterpret_cast<const float4*>(Bt + (long long)rowB[j] * 1024 + off + colB[j]);
    }
#pragma unroll
    for (int kc = 0; kc < 64; kc += 32) {
      short8 a[4], b[4];
#pragma unroll
      for (int t = 0; t < 4; ++t) {
        a[t] = *reinterpret_cast<const short8*>(Ac + (t * 16 + lr) * 72 + kc + lq8);
        b[t] = *reinterpret_cast<const short8*>(Bc + ((w << 6) + t * 16 + lr) * 72 + kc + lq8);
      }
#pragma unroll
      for (int ti = 0; ti < 4; ++ti)
#pragma unroll
        for (int tj = 0; tj < 4; ++tj)
          acc[ti][tj] =
              __builtin_amdgcn_mfma_f32_16x16x32_bf16(a[ti], b[tj], acc[ti][tj], 0, 0, 0);
    }
    if (s < 15) {
      u16* An = (s & 1) ? As0 : As1;
      u16* Bn = (s & 1) ? Bs0 : Bs1;
#pragma unroll
      for (int j = 0; j < 2; ++j)
        *reinterpret_cast<float4*>(An + rowA[j] * 72 + colA[j]) = pa[j];
#pragma unroll
      for (int j = 0; j < 8; ++j)
        *reinterpret_cast<float4*>(Bn + rowB[j] * 72 + colB[j]) = pb[j];
    }
    __syncthreads();
  }

  // ---- T (+addsrc) -> Ts in A-operand layout; zero accs ----
#pragma unroll
  for (int ti = 0; ti < 4; ++ti)
#pragma unroll
    for (int tj = 0; tj < 4; ++tj)
#pragma unroll
      for (int r = 0; r < 4; ++r) {
        int row = ti * 16 + lq4 + r;
        int col = (w << 6) + tj * 16 + lr;
        float v = acc[ti][tj][r] + bf2f(addb[(long long)(m0 + row) * ldadd + col]);
        Ts[row * 264 + col] = f2bf(v);
        acc[ti][tj][r] = 0.f;
      }
  // prologue stage 2: Wg slab 0 -> Ws0
  float4 pw[8];
#pragma unroll
  for (int j = 0; j < 8; ++j)
    pw[j] = *reinterpret_cast<const float4*>(Wg + (long long)rowB[j] * 256 + colB[j]);
#pragma unroll
  for (int j = 0; j < 8; ++j)
    *reinterpret_cast<float4*>(Ws0 + rowB[j] * 72 + colB[j]) = pw[j];
  __syncthreads();

  // ---- stage 2: out = T @ Wg^T, K=256, 4 slabs, dbuf ----
  for (int s = 0; s < 4; ++s) {
    const u16* Wc = (s & 1) ? Ws1 : Ws0;
    int kc0 = s << 6;
    if (s < 3) {
      int off = (s + 1) << 6;
#pragma unroll
      for (int j = 0; j < 8; ++j)
        pw[j] = *reinterpret_cast<const float4*>(Wg + (long long)rowB[j] * 256 + off + colB[j]);
    }
#pragma unroll
    for (int kc = 0; kc < 64; kc += 32) {
      short8 a[4], b[4];
#pragma unroll
      for (int t = 0; t < 4; ++t) {
        a[t] = *reinterpret_cast<const short8*>(Ts + (t * 16 + lr) * 264 + kc0 + kc + lq8);
        b[t] = *reinterpret_cast<const short8*>(Wc + ((w << 6) + t * 16 + lr) * 72 + kc + lq8);
      }
#pragma unroll
      for (int ti = 0; ti < 4; ++ti)
#pragma unroll
        for (int tj = 0; tj < 4; ++tj)
          acc[ti][tj] =
              __builtin_amdgcn_mfma_f32_16x16x32_bf16(a[ti], b[tj], acc[ti][tj], 0, 0, 0);
    }
    if (s < 3) {
      u16* Wn = (s & 1) ? Ws0 : Ws1;
#pragma unroll
      for (int j = 0; j < 8; ++j)
        *reinterpret_cast<float4*>(Wn + rowB[j] * 72 + colB[j]) = pw[j];
    }
    __syncthreads();
  }

  // ---- epilogue: relu((. + 2b)/den) -> fin slice (+obT K-major, layer 0) ----
  const float* bb = bg_all + idx2 * 256;
  const float* dn = den + (z << 10);
  long long finbase = (long long)(z & 3) * 2097152 + idx2 * 256;
#pragma unroll
  for (int ti = 0; ti < 4; ++ti) {
    int row = m0 + ti * 16 + lq4;
#pragma unroll
    for (int tj = 0; tj < 4; ++tj) {
      int col = (w << 6) + tj * 16 + lr;
      u16 bv4[4];
#pragma unroll
      for (int r = 0; r < 4; ++r) {
        float v = (acc[ti][tj][r] + 2.f * bb[col]) / dn[row + r];
        v = fmaxf(v, 0.f);
        bv4[r] = f2bf(v);
        fin[finbase + (long long)(row + r) * 2048 + col] = bv4[r];
      }
      if (obT) {
        ushort4 t4 = {bv4[0], bv4[1], bv4[2], bv4[3]};
        *reinterpret_cast<ushort4*>(obT + ((long long)z << 18) +
                                    (long long)col * 1024 + row) = t4;
      }
    }
  }
}

// ---- final split-K: out += fin @ Wo^T (atomic f32) -------------------------
__global__ __launch_bounds__(256) void mfinal_k(
    const u16* __restrict__ fin, const u16* __restrict__ WoT,
    float* __restrict__ out) {
  __shared__ u16 As[2 * 64 * LDS_P], Bs[2 * 64 * LDS_P];
  int m0 = blockIdx.y << 6, n0 = blockIdx.x << 6;
  int ks = blockIdx.z << 9;
  floatx4 acc[2][2] = {};
  mfma_loop(fin + (long long)m0 * 2048 + ks, 2048, WoT + (long long)n0 * 2048 + ks,
            2048, 512, As, Bs, acc, threadIdx.x);
  EPI_SETUP
#pragma unroll
  for (int ti = 0; ti < 2; ++ti)
#pragma unroll
    for (int tj = 0; tj < 2; ++tj)
#pragma unroll
      for (int r = 0; r < 4; ++r) {
        int row = m0 + wm + ti * 16 + lq4 + r;
        int col = n0 + wn + tj * 16 + lr;
        atomicAdd(out + (long long)row * 256 + col, acc[ti][tj][r]);
      }
}

// ---- prep: LDS-tiled transposes + concat + out init (one launch) -----------
__global__ __launch_bounds__(256) void prep_k(
    const float* __restrict__ X, const float* __restrict__ R,
    const float* __restrict__ W_Q, const float* __restrict__ W_K,
    const float* __restrict__ W_gcn, const float* __restrict__ W_out,
    const float* __restrict__ b_out,
    u16* __restrict__ A, u16* __restrict__ XT, u16* __restrict__ WQT,
    u16* __restrict__ WKT, u16* __restrict__ WgT, u16* __restrict__ WoT,
    float* __restrict__ out) {
  int bi = blockIdx.x;
  int tid = threadIdx.x;
  if (bi < 560) {
    __shared__ u16 tile[64 * LDS_P];
    const float* S;
    u16* D;
    int I, ti, tj;
    if (bi < 256) {  // XT: [4] 1024x256 -> 256x1024
      int zz = bi >> 6, rem = bi & 63;
      ti = rem >> 2; tj = rem & 3; I = 1024;
      S = X + zz * 262144; D = XT + zz * 262144;
    } else if (bi < 288) {  // WQT: 512x256 -> 256x512
      int t = bi - 256; ti = t >> 2; tj = t & 3; I = 512;
      S = W_Q; D = WQT;
    } else if (bi < 304) {  // WKT
      int t = bi - 288; ti = t >> 2; tj = t & 3; I = 256;
      S = W_K; D = WKT;
    } else if (bi < 432) {  // WgT: [8] 256x256
      int t = bi - 304; int zz = t >> 4, rem = t & 15;
      ti = rem >> 2; tj = rem & 3; I = 256;
      S = W_gcn + zz * 65536; D = WgT + zz * 65536;
    } else {  // WoT: 2048x256 -> 256x2048
      int t = bi - 432; ti = t >> 2; tj = t & 3; I = 2048;
      S = W_out; D = WoT;
    }
    int rr = tid >> 4, cc = (tid & 15) << 2;
#pragma unroll
    for (int q = 0; q < 4; ++q) {
      int r = rr + (q << 4);
      float4 v = *reinterpret_cast<const float4*>(S + (long long)(ti * 64 + r) * 256 +
                                                  tj * 64 + cc);
      ushort4 h = {f2bf(v.x), f2bf(v.y), f2bf(v.z), f2bf(v.w)};
      *reinterpret_cast<ushort4*>(tile + r * LDS_P + cc) = h;
    }
    __syncthreads();
    int jl = tid >> 2, il = (tid & 3) << 4;
    u16 vals[16];
#pragma unroll
    for (int u = 0; u < 16; ++u) vals[u] = tile[(il + u) * LDS_P + jl];
    u16* dp = D + (long long)(tj * 64 + jl) * I + ti * 64 + il;
    reinterpret_cast<uint4*>(dp)[0] = *reinterpret_cast<uint4*>(vals);
    reinterpret_cast<uint4*>(dp)[1] = *reinterpret_cast<uint4*>(vals + 8);
  } else if (bi < 8752) {  // concat A = [X|R] bf16
    int gid = (bi - 560) * 256 + tid;
    int col = gid & 511, row = gid >> 9;
    float v = (col < 256) ? X[row * 256 + col] : R[row * 256 + col - 256];
    A[gid] = f2bf(v);
  } else {  // out = X + b_out (float4 units)
    int t = (bi - 8752) * 256 + tid;
    int col = (t << 2) & 255;
    float4 x = reinterpret_cast<const float4*>(X)[t];
    float4 b = *reinterpret_cast<const float4*>(b_out + col);
    x.x += b.x; x.y += b.y; x.z += b.z; x.w += b.w;
    reinterpret_cast<float4*>(out)[t] = x;
  }
}

// ---- launch ----------------------------------------------------------------
extern "C" void kernel_launch(void* const* d_in, const int* in_sizes, int n_in,
                              void* d_out, int out_size, void* d_ws, size_t ws_size,
                              hipStream_t stream) {
  const float* X = (const float*)d_in[0];
  const float* R = (const float*)d_in[1];
  const int* adj = (const int*)d_in[2];
  const int* mask = (const int*)d_in[3];
  const float* W_Q = (const float*)d_in[4];
  const float* b_Q = (const float*)d_in[5];
  const float* W_K = (const float*)d_in[6];
  const float* b_K = (const float*)d_in[7];
  const float* W_gcn = (const float*)d_in[8];
  const float* b_gcn = (const float*)d_in[9];
  const float* W_out = (const float*)d_in[10];
  const float* b_out = (const float*)d_in[11];
  float* out = (float*)d_out;

  u16* wsu = (u16*)d_ws;
  u16* A_qk = wsu;                        // [4096][512]      2M u16
  u16* qbf  = A_qk + (2u << 20);          // [4096][256]      1M
  u16* kbf  = qbf + (1u << 20);           // [4096][256]      1M
  u16* XT   = kbf + (1u << 20);           // [4][256][1024]   1M
  u16* WQT  = XT + (1u << 20);            // [256][512]       128K
  u16* WKT  = WQT + (1u << 17);           // [256][256]       64K
  u16* WgT  = WKT + (1u << 16);           // [8][256][256]    512K
  u16* WoT  = WgT + (1u << 19);           // [256][2048]      512K
  u16* obT  = WoT + (1u << 19);           // [16][256][1024]  4M
  u16* finb = obT + (4u << 20);           // [4][1024][2048]  8M
  u16* wght = finb + (8u << 20);          // [16][1024][1024] 16M
  float* den = (float*)(wght + (16u << 20));   // [16][1024] f32
  u16* sc = (u16*)(den + (1 << 14));           // [16][1024][1024] bf16 (32 MB)

  // prep: tiled transposes + concat + out init
  prep_k<<<9776, 256, 0, stream>>>(X, R, W_Q, W_K, W_gcn, W_out, b_out,
                                   A_qk, XT, WQT, WKT, WgT, WoT, out);

  // q & k projections
  proj2_k<<<dim3(4, 64, 2), 256, 0, stream>>>(A_qk, WQT, WKT, b_Q, b_K, qbf, kbf);

  // scores (bf16) + z-score chain (wave-per-row)
  mscore_k<<<dim3(16, 16, 16), 256, 0, stream>>>(qbf, kbf, sc);
  zscore_w<<<1024, 256, 0, stream>>>(sc, adj, mask, wght, den);

  // fused GCN layers (dbuf); layer 1 reads +src from finb
  gcn_k<<<dim3(16, 16), 256, 0, stream>>>(wght, XT, 3, A_qk, 512, 524288LL, 0,
                                          WgT, b_gcn, den, 0, obT, finb);
  gcn_k<<<dim3(16, 16), 256, 0, stream>>>(wght, obT, 15, finb, 2048, 2097152LL, 512,
                                          WgT, b_gcn, den, 1, nullptr, finb);

  // final split-K accumulate
  mfinal_k<<<dim3(4, 64, 4), 256, 0, stream>>>(finb, WoT, out);
}

// Round 11
// 212.710 us; speedup vs baseline: 1.0685x; 1.0685x over previous
//
#include <hip/hip_runtime.h>
#include <math.h>

typedef unsigned short u16;
typedef __attribute__((ext_vector_type(8))) short short8;
typedef __attribute__((ext_vector_type(4))) float floatx4;

#define LDS_P 72  // padded LDS row stride for 64-wide tiles

__device__ __forceinline__ float bf2f(u16 u) {
  union { unsigned int i; float f; } v; v.i = ((unsigned int)u) << 16; return v.f;
}
__device__ __forceinline__ u16 f2bf(float f) {
  union { float f; unsigned int i; } v; v.f = f;
  unsigned int x = v.i;
  return (u16)((x + 0x7FFFu + ((x >> 16) & 1u)) >> 16);
}

// ---- core 64x64 tile loop, LDS double-buffered, one barrier per K-slab -----
__device__ __forceinline__ void mfma_loop(const u16* __restrict__ A, int lda,
                                          const u16* __restrict__ Bt, int ldb,
                                          int K, u16* As, u16* Bs,
                                          floatx4 acc[2][2], int tid) {
  int lane = tid & 63;
  int wm = ((tid >> 6) & 1) << 5, wn = ((tid >> 6) >> 1) << 5;
  int lr = lane & 15, lq8 = (lane >> 4) << 3;
  int r0 = tid >> 3, c8 = (tid & 7) << 3;

  const u16* pA0 = A + (long long)r0 * lda + c8;
  const u16* pA1 = A + (long long)(r0 + 32) * lda + c8;
  const u16* pB0 = Bt + (long long)r0 * ldb + c8;
  const u16* pB1 = Bt + (long long)(r0 + 32) * ldb + c8;
  float4 a0 = *reinterpret_cast<const float4*>(pA0);
  float4 a1 = *reinterpret_cast<const float4*>(pA1);
  float4 b0 = *reinterpret_cast<const float4*>(pB0);
  float4 b1 = *reinterpret_cast<const float4*>(pB1);
  *reinterpret_cast<float4*>(As + r0 * LDS_P + c8) = a0;
  *reinterpret_cast<float4*>(As + (r0 + 32) * LDS_P + c8) = a1;
  *reinterpret_cast<float4*>(Bs + r0 * LDS_P + c8) = b0;
  *reinterpret_cast<float4*>(Bs + (r0 + 32) * LDS_P + c8) = b1;
  __syncthreads();

  int nslab = K >> 6;
  for (int s = 0; s < nslab; ++s) {
    const u16* Ac = As + (s & 1) * 4608;
    const u16* Bc = Bs + (s & 1) * 4608;
    if (s + 1 < nslab) {
      int off = (s + 1) << 6;
      a0 = *reinterpret_cast<const float4*>(pA0 + off);
      a1 = *reinterpret_cast<const float4*>(pA1 + off);
      b0 = *reinterpret_cast<const float4*>(pB0 + off);
      b1 = *reinterpret_cast<const float4*>(pB1 + off);
    }
#pragma unroll
    for (int kc = 0; kc < 64; kc += 32) {
      short8 fa0 = *reinterpret_cast<const short8*>(Ac + (wm + lr) * LDS_P + kc + lq8);
      short8 fa1 = *reinterpret_cast<const short8*>(Ac + (wm + 16 + lr) * LDS_P + kc + lq8);
      short8 fb0 = *reinterpret_cast<const short8*>(Bc + (wn + lr) * LDS_P + kc + lq8);
      short8 fb1 = *reinterpret_cast<const short8*>(Bc + (wn + 16 + lr) * LDS_P + kc + lq8);
      acc[0][0] = __builtin_amdgcn_mfma_f32_16x16x32_bf16(fa0, fb0, acc[0][0], 0, 0, 0);
      acc[0][1] = __builtin_amdgcn_mfma_f32_16x16x32_bf16(fa0, fb1, acc[0][1], 0, 0, 0);
      acc[1][0] = __builtin_amdgcn_mfma_f32_16x16x32_bf16(fa1, fb0, acc[1][0], 0, 0, 0);
      acc[1][1] = __builtin_amdgcn_mfma_f32_16x16x32_bf16(fa1, fb1, acc[1][1], 0, 0, 0);
    }
    if (s + 1 < nslab) {
      u16* An = As + ((s + 1) & 1) * 4608;
      u16* Bn = Bs + ((s + 1) & 1) * 4608;
      *reinterpret_cast<float4*>(An + r0 * LDS_P + c8) = a0;
      *reinterpret_cast<float4*>(An + (r0 + 32) * LDS_P + c8) = a1;
      *reinterpret_cast<float4*>(Bn + r0 * LDS_P + c8) = b0;
      *reinterpret_cast<float4*>(Bn + (r0 + 32) * LDS_P + c8) = b1;
    }
    __syncthreads();
  }
}

#define EPI_SETUP                                                     \
  int lane = threadIdx.x & 63;                                        \
  int wm = ((threadIdx.x >> 6) & 1) << 5,                             \
      wn = ((threadIdx.x >> 6) >> 1) << 5;                            \
  int lr = lane & 15, lq4 = (lane >> 4) << 2;

// ---- q+k projections in one launch (z=0:Q, z=1:K) --------------------------
__global__ __launch_bounds__(256) void proj2_k(
    const u16* __restrict__ A, const u16* __restrict__ WQT,
    const u16* __restrict__ WKT, const float* __restrict__ b_Q,
    const float* __restrict__ b_K, u16* __restrict__ qbf,
    u16* __restrict__ kbf) {
  __shared__ u16 As[2 * 64 * LDS_P], Bs[2 * 64 * LDS_P];
  int z = blockIdx.z;
  int m0 = blockIdx.y << 6, n0 = blockIdx.x << 6;
  int K = z ? 256 : 512, ldb = z ? 256 : 512;
  const u16* Bt = z ? WKT : WQT;
  const float* bias = z ? b_K : b_Q;
  u16* C = z ? kbf : qbf;
  floatx4 acc[2][2] = {};
  mfma_loop(A + (long long)m0 * 512, 512, Bt + (long long)n0 * ldb, ldb, K, As, Bs,
            acc, threadIdx.x);
  EPI_SETUP
#pragma unroll
  for (int ti = 0; ti < 2; ++ti)
#pragma unroll
    for (int tj = 0; tj < 2; ++tj)
#pragma unroll
      for (int r = 0; r < 4; ++r) {
        int row = m0 + wm + ti * 16 + lq4 + r;
        int col = n0 + wn + tj * 16 + lr;
        C[(long long)row * 256 + col] = f2bf(acc[ti][tj][r] + bias[col]);
      }
}

// ---- scores, all 16 z-slices (z = h*4+b), bf16 output ----------------------
__global__ __launch_bounds__(256) void mscore_k(
    const u16* __restrict__ q, const u16* __restrict__ kb,
    u16* __restrict__ sc) {
  __shared__ u16 As[2 * 64 * LDS_P], Bs[2 * 64 * LDS_P];
  int z = blockIdx.z;
  int b = z & 3, h = z >> 2;
  int m0 = blockIdx.y << 6, n0 = blockIdx.x << 6;
  const u16* Ab = q + b * 262144 + h * 64;
  const u16* Bb = kb + b * 262144 + h * 64;
  floatx4 acc[2][2] = {};
  mfma_loop(Ab + (long long)m0 * 256, 256, Bb + (long long)n0 * 256, 256, 64, As, Bs,
            acc, threadIdx.x);
  u16* Cb = sc + ((long long)z << 20);
  EPI_SETUP
#pragma unroll
  for (int ti = 0; ti < 2; ++ti)
#pragma unroll
    for (int tj = 0; tj < 2; ++tj)
#pragma unroll
      for (int r = 0; r < 4; ++r) {
        int row = m0 + wm + ti * 16 + lq4 + r;
        int col = n0 + wn + tj * 16 + lr;
        Cb[(long long)row * 1024 + col] = f2bf(acc[ti][tj][r]);
      }
}

// ---- wave-level reductions (no barriers) -----------------------------------
__device__ __forceinline__ float wred_sum(float v) {
#pragma unroll
  for (int m = 32; m > 0; m >>= 1) v += __shfl_xor(v, m, 64);
  return v;
}
__device__ __forceinline__ void wred_sum2(float& a, float& b) {
#pragma unroll
  for (int m = 32; m > 0; m >>= 1) {
    float ta = __shfl_xor(a, m, 64);
    float tb = __shfl_xor(b, m, 64);
    a += ta; b += tb;
  }
}
__device__ __forceinline__ float wred_max(float v) {
#pragma unroll
  for (int m = 32; m > 0; m >>= 1) v = fmaxf(v, __shfl_xor(v, m, 64));
  return v;
}

// ---- z-score attention: one wave per row, all 4 heads ----------------------
__global__ __launch_bounds__(256) void zscore_w(
    const u16* __restrict__ sc, const int* __restrict__ adj,
    const int* __restrict__ mask, u16* __restrict__ wout,
    float* __restrict__ denh) {
  int wv = threadIdx.x >> 6, lane = threadIdx.x & 63;
  int row = (blockIdx.x << 2) + wv;
  int b = row >> 10, n = row & 1023;
  int e0 = lane << 4;
  const int* arow = adj + ((long long)row << 10) + e0;
  const int* mrow = mask + (b << 10) + e0;

  unsigned int vbits = 0, abits = 0;
#pragma unroll
  for (int q = 0; q < 4; ++q) {
    int4 a4 = *reinterpret_cast<const int4*>(arow + (q << 2));
    int4 m4 = *reinterpret_cast<const int4*>(mrow + (q << 2));
    vbits |= (unsigned)(m4.x == 0) << (q * 4);
    vbits |= (unsigned)(m4.y == 0) << (q * 4 + 1);
    vbits |= (unsigned)(m4.z == 0) << (q * 4 + 2);
    vbits |= (unsigned)(m4.w == 0) << (q * 4 + 3);
    abits |= (unsigned)(a4.x != 0) << (q * 4);
    abits |= (unsigned)(a4.y != 0) << (q * 4 + 1);
    abits |= (unsigned)(a4.z != 0) << (q * 4 + 2);
    abits |= (unsigned)(a4.w != 0) << (q * 4 + 3);
  }
  float cnt = wred_sum((float)__popc(vbits));
  float cnteff = cnt + 0.0001f;

  for (int h = 0; h < 4; ++h) {
    int z = (h << 2) + b;
    const u16* srow = sc + ((long long)z << 20) + ((long long)n << 10) + e0;
    float s[16];
#pragma unroll
    for (int q = 0; q < 2; ++q) {
      uint4 u = *reinterpret_cast<const uint4*>(srow + (q << 3));
      unsigned int uu[4] = {u.x, u.y, u.z, u.w};
#pragma unroll
      for (int t = 0; t < 4; ++t) {
        union { unsigned int i; float f; } lo, hi;
        lo.i = uu[t] << 16;
        hi.i = uu[t] & 0xffff0000u;
        s[q * 8 + t * 2] = lo.f;
        s[q * 8 + t * 2 + 1] = hi.f;
      }
    }
    float suml = 0.f, sql = 0.f;
#pragma unroll
    for (int u = 0; u < 16; ++u)
      if ((vbits >> u) & 1) { suml += s[u]; sql += s[u] * s[u]; }
    wred_sum2(suml, sql);
    float mean = suml / cnteff;
    float sdata = sql - 2.f * mean * suml + cnt * mean * mean;
    float stdv = sqrtf(fmaxf(sdata, 0.f) / cnteff + 1e-10f);
    float inv = 1.f / (stdv + 0.0001f);

    float maxl = -1e9f;
#pragma unroll
    for (int u = 0; u < 16; ++u) {
      float zz = (s[u] - mean) * inv;
      int vv = (vbits >> u) & 1;
      zz = vv ? zz : 0.f;
      s[u] = zz;
      if (vv && zz >= 0.f) maxl = fmaxf(maxl, zz);
    }
    float rowmax = wred_max(maxl);

    float e[16], el = 0.f;
#pragma unroll
    for (int u = 0; u < 16; ++u) {
      int vv = (vbits >> u) & 1, aa = (abits >> u) & 1;
      float ev = (vv && aa && (s[u] >= 0.f)) ? expf(s[u] - rowmax) : 0.f;
      e[u] = ev + 1e-10f;
      el += e[u];
    }
    float esum = wred_sum(el);
    float rinv = 1.f / esum;

    float wl = 0.f;
    unsigned int wo[8];
#pragma unroll
    for (int u = 0; u < 16; u += 2) {
      int s0 = ((vbits >> u) & 1) && ((abits >> u) & 1) && (s[u] >= 0.f);
      int s1 = ((vbits >> (u + 1)) & 1) && ((abits >> (u + 1)) & 1) && (s[u + 1] >= 0.f);
      float w0 = s0 ? e[u] * rinv : 0.f;
      float w1 = s1 ? e[u + 1] * rinv : 0.f;
      wl += w0 + w1;
      wo[u >> 1] = (unsigned)f2bf(w0) | ((unsigned)f2bf(w1) << 16);
    }
    float wsum = wred_sum(wl);

    u16* orow = wout + ((size_t)z << 20) + ((size_t)n << 10) + e0;
    reinterpret_cast<uint4*>(orow)[0] = make_uint4(wo[0], wo[1], wo[2], wo[3]);
    reinterpret_cast<uint4*>(orow)[1] = make_uint4(wo[4], wo[5], wo[6], wo[7]);
    if (lane == 0) denh[(z << 10) + n] = wsum + 1.0f;
  }
}

// ---- fused GCN layer: 512 threads (8 waves = 2/SIMD), dbuf both stages -----
// Block tile 64x256; wave tile 32x64 (acc 2x4).
__global__ __launch_bounds__(512) void gcn_k(
    const u16* __restrict__ wght, const u16* __restrict__ srcT, int zmaskB,
    const u16* __restrict__ addsrc, int ldadd, long long sAdd, int hmul,
    const u16* __restrict__ WgT_all, const float* __restrict__ bg_all,
    const float* __restrict__ den, int l,
    u16* __restrict__ obT, u16* __restrict__ fin) {
  __shared__ u16 lds[53760];  // 107.5 KB
  u16* As0 = lds;             // [64][72]
  u16* As1 = lds + 4608;
  u16* Bs0 = lds + 9216;      // [256][72]
  u16* Bs1 = lds + 27648;
  u16* Ts = lds;              // [64][264] (stage 2, overlays stage-1 A/B0)
  u16* Ws0 = lds + 16896;     // [256][72]
  u16* Ws1 = lds + 35328;
  int tid = threadIdx.x;
  int m0 = blockIdx.x << 6;
  int z = blockIdx.y;
  int lane = tid & 63, w = tid >> 6;
  int wm = (w & 1) << 5, wn = (w >> 1) << 6;  // wave tile: rows wm..wm+31, cols wn..wn+63
  int lr = lane & 15, lq8 = (lane >> 4) << 3, lq4 = (lane >> 4) << 2;

  const u16* Aw = wght + ((long long)z << 20) + (long long)m0 * 1024;
  const u16* Bt = srcT + (long long)(z & zmaskB) * 262144;
  const u16* addb = addsrc + (long long)(z & 3) * sAdd + (z >> 2) * hmul;
  int idx2 = (z >> 2) * 2 + l;
  const u16* Wg = WgT_all + (long long)idx2 * 65536;

  floatx4 acc[2][4] = {};
  // staging index maps (512 threads)
  int rA = tid >> 3, cA = (tid & 7) << 3;  // A: 64x64 -> 1 float4/thread
  int rowB[4], colB[4];                    // B/W: 256x64 -> 4 float4/thread
#pragma unroll
  for (int j = 0; j < 4; ++j) {
    int id = tid + (j << 9);
    rowB[j] = id >> 3; colB[j] = (id & 7) << 3;
  }

  float4 pa, pb[4];
  // prologue: slab 0 -> buf0
  pa = *reinterpret_cast<const float4*>(Aw + (long long)rA * 1024 + cA);
#pragma unroll
  for (int j = 0; j < 4; ++j)
    pb[j] = *reinterpret_cast<const float4*>(Bt + (long long)rowB[j] * 1024 + colB[j]);
  *reinterpret_cast<float4*>(As0 + rA * 72 + cA) = pa;
#pragma unroll
  for (int j = 0; j < 4; ++j)
    *reinterpret_cast<float4*>(Bs0 + rowB[j] * 72 + colB[j]) = pb[j];
  __syncthreads();

  // ---- stage 1: K=1024, 16 slabs ----
  for (int s = 0; s < 16; ++s) {
    const u16* Ac = (s & 1) ? As1 : As0;
    const u16* Bc = (s & 1) ? Bs1 : Bs0;
    if (s < 15) {
      int off = (s + 1) << 6;
      pa = *reinterpret_cast<const float4*>(Aw + (long long)rA * 1024 + off + cA);
#pragma unroll
      for (int j = 0; j < 4; ++j)
        pb[j] = *reinterpret_cast<const float4*>(Bt + (long long)rowB[j] * 1024 + off + colB[j]);
    }
#pragma unroll
    for (int kc = 0; kc < 64; kc += 32) {
      short8 a[2], b[4];
#pragma unroll
      for (int t = 0; t < 2; ++t)
        a[t] = *reinterpret_cast<const short8*>(Ac + (wm + t * 16 + lr) * 72 + kc + lq8);
#pragma unroll
      for (int t = 0; t < 4; ++t)
        b[t] = *reinterpret_cast<const short8*>(Bc + (wn + t * 16 + lr) * 72 + kc + lq8);
#pragma unroll
      for (int ti = 0; ti < 2; ++ti)
#pragma unroll
        for (int tj = 0; tj < 4; ++tj)
          acc[ti][tj] =
              __builtin_amdgcn_mfma_f32_16x16x32_bf16(a[ti], b[tj], acc[ti][tj], 0, 0, 0);
    }
    if (s < 15) {
      u16* An = (s & 1) ? As0 : As1;
      u16* Bn = (s & 1) ? Bs0 : Bs1;
      *reinterpret_cast<float4*>(An + rA * 72 + cA) = pa;
#pragma unroll
      for (int j = 0; j < 4; ++j)
        *reinterpret_cast<float4*>(Bn + rowB[j] * 72 + colB[j]) = pb[j];
    }
    __syncthreads();
  }

  // ---- T (+addsrc) -> Ts in A-operand layout; zero accs ----
#pragma unroll
  for (int ti = 0; ti < 2; ++ti)
#pragma unroll
    for (int tj = 0; tj < 4; ++tj)
#pragma unroll
      for (int r = 0; r < 4; ++r) {
        int row = wm + ti * 16 + lq4 + r;
        int col = wn + tj * 16 + lr;
        float v = acc[ti][tj][r] + bf2f(addb[(long long)(m0 + row) * ldadd + col]);
        Ts[row * 264 + col] = f2bf(v);
        acc[ti][tj][r] = 0.f;
      }
  // prologue stage 2: Wg slab 0 -> Ws0
  float4 pw[4];
#pragma unroll
  for (int j = 0; j < 4; ++j)
    pw[j] = *reinterpret_cast<const float4*>(Wg + (long long)rowB[j] * 256 + colB[j]);
#pragma unroll
  for (int j = 0; j < 4; ++j)
    *reinterpret_cast<float4*>(Ws0 + rowB[j] * 72 + colB[j]) = pw[j];
  __syncthreads();

  // ---- stage 2: out = T @ Wg^T, K=256, 4 slabs ----
  for (int s = 0; s < 4; ++s) {
    const u16* Wc = (s & 1) ? Ws1 : Ws0;
    int kc0 = s << 6;
    if (s < 3) {
      int off = (s + 1) << 6;
#pragma unroll
      for (int j = 0; j < 4; ++j)
        pw[j] = *reinterpret_cast<const float4*>(Wg + (long long)rowB[j] * 256 + off + colB[j]);
    }
#pragma unroll
    for (int kc = 0; kc < 64; kc += 32) {
      short8 a[2], b[4];
#pragma unroll
      for (int t = 0; t < 2; ++t)
        a[t] = *reinterpret_cast<const short8*>(Ts + (wm + t * 16 + lr) * 264 + kc0 + kc + lq8);
#pragma unroll
      for (int t = 0; t < 4; ++t)
        b[t] = *reinterpret_cast<const short8*>(Wc + (wn + t * 16 + lr) * 72 + kc + lq8);
#pragma unroll
      for (int ti = 0; ti < 2; ++ti)
#pragma unroll
        for (int tj = 0; tj < 4; ++tj)
          acc[ti][tj] =
              __builtin_amdgcn_mfma_f32_16x16x32_bf16(a[ti], b[tj], acc[ti][tj], 0, 0, 0);
    }
    if (s < 3) {
      u16* Wn = (s & 1) ? Ws0 : Ws1;
#pragma unroll
      for (int j = 0; j < 4; ++j)
        *reinterpret_cast<float4*>(Wn + rowB[j] * 72 + colB[j]) = pw[j];
    }
    __syncthreads();
  }

  // ---- epilogue: relu((. + 2b)/den) -> fin slice (+obT K-major, layer 0) ----
  const float* bb = bg_all + idx2 * 256;
  const float* dn = den + (z << 10);
  long long finbase = (long long)(z & 3) * 2097152 + idx2 * 256;
#pragma unroll
  for (int ti = 0; ti < 2; ++ti) {
    int row = m0 + wm + ti * 16 + lq4;
#pragma unroll
    for (int tj = 0; tj < 4; ++tj) {
      int col = wn + tj * 16 + lr;
      u16 bv4[4];
#pragma unroll
      for (int r = 0; r < 4; ++r) {
        float v = (acc[ti][tj][r] + 2.f * bb[col]) / dn[row + r];
        v = fmaxf(v, 0.f);
        bv4[r] = f2bf(v);
        fin[finbase + (long long)(row + r) * 2048 + col] = bv4[r];
      }
      if (obT) {
        ushort4 t4 = {bv4[0], bv4[1], bv4[2], bv4[3]};
        *reinterpret_cast<ushort4*>(obT + ((long long)z << 18) +
                                    (long long)col * 1024 + row) = t4;
      }
    }
  }
}

// ---- final split-K: out += fin @ Wo^T (atomic f32) -------------------------
__global__ __launch_bounds__(256) void mfinal_k(
    const u16* __restrict__ fin, const u16* __restrict__ WoT,
    float* __restrict__ out) {
  __shared__ u16 As[2 * 64 * LDS_P], Bs[2 * 64 * LDS_P];
  int m0 = blockIdx.y << 6, n0 = blockIdx.x << 6;
  int ks = blockIdx.z << 9;
  floatx4 acc[2][2] = {};
  mfma_loop(fin + (long long)m0 * 2048 + ks, 2048, WoT + (long long)n0 * 2048 + ks,
            2048, 512, As, Bs, acc, threadIdx.x);
  EPI_SETUP
#pragma unroll
  for (int ti = 0; ti < 2; ++ti)
#pragma unroll
    for (int tj = 0; tj < 2; ++tj)
#pragma unroll
      for (int r = 0; r < 4; ++r) {
        int row = m0 + wm + ti * 16 + lq4 + r;
        int col = n0 + wn + tj * 16 + lr;
        atomicAdd(out + (long long)row * 256 + col, acc[ti][tj][r]);
      }
}

// ---- prep: LDS-tiled transposes + concat + out init (one launch) -----------
__global__ __launch_bounds__(256) void prep_k(
    const float* __restrict__ X, const float* __restrict__ R,
    const float* __restrict__ W_Q, const float* __restrict__ W_K,
    const float* __restrict__ W_gcn, const float* __restrict__ W_out,
    const float* __restrict__ b_out,
    u16* __restrict__ A, u16* __restrict__ XT, u16* __restrict__ WQT,
    u16* __restrict__ WKT, u16* __restrict__ WgT, u16* __restrict__ WoT,
    float* __restrict__ out) {
  int bi = blockIdx.x;
  int tid = threadIdx.x;
  if (bi < 560) {
    __shared__ u16 tile[64 * LDS_P];
    const float* S;
    u16* D;
    int I, ti, tj;
    if (bi < 256) {  // XT: [4] 1024x256 -> 256x1024
      int zz = bi >> 6, rem = bi & 63;
      ti = rem >> 2; tj = rem & 3; I = 1024;
      S = X + zz * 262144; D = XT + zz * 262144;
    } else if (bi < 288) {  // WQT: 512x256 -> 256x512
      int t = bi - 256; ti = t >> 2; tj = t & 3; I = 512;
      S = W_Q; D = WQT;
    } else if (bi < 304) {  // WKT
      int t = bi - 288; ti = t >> 2; tj = t & 3; I = 256;
      S = W_K; D = WKT;
    } else if (bi < 432) {  // WgT: [8] 256x256
      int t = bi - 304; int zz = t >> 4, rem = t & 15;
      ti = rem >> 2; tj = rem & 3; I = 256;
      S = W_gcn + zz * 65536; D = WgT + zz * 65536;
    } else {  // WoT: 2048x256 -> 256x2048
      int t = bi - 432; ti = t >> 2; tj = t & 3; I = 2048;
      S = W_out; D = WoT;
    }
    int rr = tid >> 4, cc = (tid & 15) << 2;
#pragma unroll
    for (int q = 0; q < 4; ++q) {
      int r = rr + (q << 4);
      float4 v = *reinterpret_cast<const float4*>(S + (long long)(ti * 64 + r) * 256 +
                                                  tj * 64 + cc);
      ushort4 h = {f2bf(v.x), f2bf(v.y), f2bf(v.z), f2bf(v.w)};
      *reinterpret_cast<ushort4*>(tile + r * LDS_P + cc) = h;
    }
    __syncthreads();
    int jl = tid >> 2, il = (tid & 3) << 4;
    u16 vals[16];
#pragma unroll
    for (int u = 0; u < 16; ++u) vals[u] = tile[(il + u) * LDS_P + jl];
    u16* dp = D + (long long)(tj * 64 + jl) * I + ti * 64 + il;
    reinterpret_cast<uint4*>(dp)[0] = *reinterpret_cast<uint4*>(vals);
    reinterpret_cast<uint4*>(dp)[1] = *reinterpret_cast<uint4*>(vals + 8);
  } else if (bi < 8752) {  // concat A = [X|R] bf16
    int gid = (bi - 560) * 256 + tid;
    int col = gid & 511, row = gid >> 9;
    float v = (col < 256) ? X[row * 256 + col] : R[row * 256 + col - 256];
    A[gid] = f2bf(v);
  } else {  // out = X + b_out (float4 units)
    int t = (bi - 8752) * 256 + tid;
    int col = (t << 2) & 255;
    float4 x = reinterpret_cast<const float4*>(X)[t];
    float4 b = *reinterpret_cast<const float4*>(b_out + col);
    x.x += b.x; x.y += b.y; x.z += b.z; x.w += b.w;
    reinterpret_cast<float4*>(out)[t] = x;
  }
}

// ---- launch ----------------------------------------------------------------
extern "C" void kernel_launch(void* const* d_in, const int* in_sizes, int n_in,
                              void* d_out, int out_size, void* d_ws, size_t ws_size,
                              hipStream_t stream) {
  const float* X = (const float*)d_in[0];
  const float* R = (const float*)d_in[1];
  const int* adj = (const int*)d_in[2];
  const int* mask = (const int*)d_in[3];
  const float* W_Q = (const float*)d_in[4];
  const float* b_Q = (const float*)d_in[5];
  const float* W_K = (const float*)d_in[6];
  const float* b_K = (const float*)d_in[7];
  const float* W_gcn = (const float*)d_in[8];
  const float* b_gcn = (const float*)d_in[9];
  const float* W_out = (const float*)d_in[10];
  const float* b_out = (const float*)d_in[11];
  float* out = (float*)d_out;

  u16* wsu = (u16*)d_ws;
  u16* A_qk = wsu;                        // [4096][512]      2M u16
  u16* qbf  = A_qk + (2u << 20);          // [4096][256]      1M
  u16* kbf  = qbf + (1u << 20);           // [4096][256]      1M
  u16* XT   = kbf + (1u << 20);           // [4][256][1024]   1M
  u16* WQT  = XT + (1u << 20);            // [256][512]       128K
  u16* WKT  = WQT + (1u << 17);           // [256][256]       64K
  u16* WgT  = WKT + (1u << 16);           // [8][256][256]    512K
  u16* WoT  = WgT + (1u << 19);           // [256][2048]      512K
  u16* obT  = WoT + (1u << 19);           // [16][256][1024]  4M
  u16* finb = obT + (4u << 20);           // [4][1024][2048]  8M
  u16* wght = finb + (8u << 20);          // [16][1024][1024] 16M
  float* den = (float*)(wght + (16u << 20));   // [16][1024] f32
  u16* sc = (u16*)(den + (1 << 14));           // [16][1024][1024] bf16 (32 MB)

  // prep: tiled transposes + concat + out init
  prep_k<<<9776, 256, 0, stream>>>(X, R, W_Q, W_K, W_gcn, W_out, b_out,
                                   A_qk, XT, WQT, WKT, WgT, WoT, out);

  // q & k projections
  proj2_k<<<dim3(4, 64, 2), 256, 0, stream>>>(A_qk, WQT, WKT, b_Q, b_K, qbf, kbf);

  // scores (bf16) + z-score chain (wave-per-row)
  mscore_k<<<dim3(16, 16, 16), 256, 0, stream>>>(qbf, kbf, sc);
  zscore_w<<<1024, 256, 0, stream>>>(sc, adj, mask, wght, den);

  // fused GCN layers (512 threads = 2 waves/SIMD); layer 1 reads +src from finb
  gcn_k<<<dim3(16, 16), 512, 0, stream>>>(wght, XT, 3, A_qk, 512, 524288LL, 0,
                                          WgT, b_gcn, den, 0, obT, finb);
  gcn_k<<<dim3(16, 16), 512, 0, stream>>>(wght, obT, 15, finb, 2048, 2097152LL, 512,
                                          WgT, b_gcn, den, 1, nullptr, finb);

  // final split-K accumulate
  mfinal_k<<<dim3(4, 64, 4), 256, 0, stream>>>(finb, WoT, out);
}

// Round 12
// 210.895 us; speedup vs baseline: 1.0777x; 1.0086x over previous
//
#include <hip/hip_runtime.h>
#include <math.h>

typedef unsigned short u16;
typedef __attribute__((ext_vector_type(8))) short short8;
typedef __attribute__((ext_vector_type(4))) float floatx4;

#define LDS_P 72  // padded LDS row stride for 64-wide tiles

__device__ __forceinline__ float bf2f(u16 u) {
  union { unsigned int i; float f; } v; v.i = ((unsigned int)u) << 16; return v.f;
}
__device__ __forceinline__ u16 f2bf(float f) {
  union { float f; unsigned int i; } v; v.f = f;
  unsigned int x = v.i;
  return (u16)((x + 0x7FFFu + ((x >> 16) & 1u)) >> 16);
}

// ---- core 64x64 tile loop, LDS double-buffered (256 threads) ---------------
__device__ __forceinline__ void mfma_loop(const u16* __restrict__ A, int lda,
                                          const u16* __restrict__ Bt, int ldb,
                                          int K, u16* As, u16* Bs,
                                          floatx4 acc[2][2], int tid) {
  int lane = tid & 63;
  int wm = ((tid >> 6) & 1) << 5, wn = ((tid >> 6) >> 1) << 5;
  int lr = lane & 15, lq8 = (lane >> 4) << 3;
  int r0 = tid >> 3, c8 = (tid & 7) << 3;

  const u16* pA0 = A + (long long)r0 * lda + c8;
  const u16* pA1 = A + (long long)(r0 + 32) * lda + c8;
  const u16* pB0 = Bt + (long long)r0 * ldb + c8;
  const u16* pB1 = Bt + (long long)(r0 + 32) * ldb + c8;
  float4 a0 = *reinterpret_cast<const float4*>(pA0);
  float4 a1 = *reinterpret_cast<const float4*>(pA1);
  float4 b0 = *reinterpret_cast<const float4*>(pB0);
  float4 b1 = *reinterpret_cast<const float4*>(pB1);
  *reinterpret_cast<float4*>(As + r0 * LDS_P + c8) = a0;
  *reinterpret_cast<float4*>(As + (r0 + 32) * LDS_P + c8) = a1;
  *reinterpret_cast<float4*>(Bs + r0 * LDS_P + c8) = b0;
  *reinterpret_cast<float4*>(Bs + (r0 + 32) * LDS_P + c8) = b1;
  __syncthreads();

  int nslab = K >> 6;
  for (int s = 0; s < nslab; ++s) {
    const u16* Ac = As + (s & 1) * 4608;
    const u16* Bc = Bs + (s & 1) * 4608;
    if (s + 1 < nslab) {
      int off = (s + 1) << 6;
      a0 = *reinterpret_cast<const float4*>(pA0 + off);
      a1 = *reinterpret_cast<const float4*>(pA1 + off);
      b0 = *reinterpret_cast<const float4*>(pB0 + off);
      b1 = *reinterpret_cast<const float4*>(pB1 + off);
    }
#pragma unroll
    for (int kc = 0; kc < 64; kc += 32) {
      short8 fa0 = *reinterpret_cast<const short8*>(Ac + (wm + lr) * LDS_P + kc + lq8);
      short8 fa1 = *reinterpret_cast<const short8*>(Ac + (wm + 16 + lr) * LDS_P + kc + lq8);
      short8 fb0 = *reinterpret_cast<const short8*>(Bc + (wn + lr) * LDS_P + kc + lq8);
      short8 fb1 = *reinterpret_cast<const short8*>(Bc + (wn + 16 + lr) * LDS_P + kc + lq8);
      acc[0][0] = __builtin_amdgcn_mfma_f32_16x16x32_bf16(fa0, fb0, acc[0][0], 0, 0, 0);
      acc[0][1] = __builtin_amdgcn_mfma_f32_16x16x32_bf16(fa0, fb1, acc[0][1], 0, 0, 0);
      acc[1][0] = __builtin_amdgcn_mfma_f32_16x16x32_bf16(fa1, fb0, acc[1][0], 0, 0, 0);
      acc[1][1] = __builtin_amdgcn_mfma_f32_16x16x32_bf16(fa1, fb1, acc[1][1], 0, 0, 0);
    }
    if (s + 1 < nslab) {
      u16* An = As + ((s + 1) & 1) * 4608;
      u16* Bn = Bs + ((s + 1) & 1) * 4608;
      *reinterpret_cast<float4*>(An + r0 * LDS_P + c8) = a0;
      *reinterpret_cast<float4*>(An + (r0 + 32) * LDS_P + c8) = a1;
      *reinterpret_cast<float4*>(Bn + r0 * LDS_P + c8) = b0;
      *reinterpret_cast<float4*>(Bn + (r0 + 32) * LDS_P + c8) = b1;
    }
    __syncthreads();
  }
}

#define EPI_SETUP                                                     \
  int lane = threadIdx.x & 63;                                        \
  int wm = ((threadIdx.x >> 6) & 1) << 5,                             \
      wn = ((threadIdx.x >> 6) >> 1) << 5;                            \
  int lr = lane & 15, lq4 = (lane >> 4) << 2;

// ---- q+k projections in one launch (z=0:Q, z=1:K) --------------------------
__global__ __launch_bounds__(256) void proj2_k(
    const u16* __restrict__ A, const u16* __restrict__ WQT,
    const u16* __restrict__ WKT, const float* __restrict__ b_Q,
    const float* __restrict__ b_K, u16* __restrict__ qbf,
    u16* __restrict__ kbf) {
  __shared__ u16 As[2 * 64 * LDS_P], Bs[2 * 64 * LDS_P];
  int z = blockIdx.z;
  int m0 = blockIdx.y << 6, n0 = blockIdx.x << 6;
  int K = z ? 256 : 512, ldb = z ? 256 : 512;
  const u16* Bt = z ? WKT : WQT;
  const float* bias = z ? b_K : b_Q;
  u16* C = z ? kbf : qbf;
  floatx4 acc[2][2] = {};
  mfma_loop(A + (long long)m0 * 512, 512, Bt + (long long)n0 * ldb, ldb, K, As, Bs,
            acc, threadIdx.x);
  EPI_SETUP
#pragma unroll
  for (int ti = 0; ti < 2; ++ti)
#pragma unroll
    for (int tj = 0; tj < 2; ++tj)
#pragma unroll
      for (int r = 0; r < 4; ++r) {
        int row = m0 + wm + ti * 16 + lq4 + r;
        int col = n0 + wn + tj * 16 + lr;
        C[(long long)row * 256 + col] = f2bf(acc[ti][tj][r] + bias[col]);
      }
}

// ---- scores, all 16 z-slices (z = h*4+b), bf16 output ----------------------
__global__ __launch_bounds__(256) void mscore_k(
    const u16* __restrict__ q, const u16* __restrict__ kb,
    u16* __restrict__ sc) {
  __shared__ u16 As[2 * 64 * LDS_P], Bs[2 * 64 * LDS_P];
  int z = blockIdx.z;
  int b = z & 3, h = z >> 2;
  int m0 = blockIdx.y << 6, n0 = blockIdx.x << 6;
  const u16* Ab = q + b * 262144 + h * 64;
  const u16* Bb = kb + b * 262144 + h * 64;
  floatx4 acc[2][2] = {};
  mfma_loop(Ab + (long long)m0 * 256, 256, Bb + (long long)n0 * 256, 256, 64, As, Bs,
            acc, threadIdx.x);
  u16* Cb = sc + ((long long)z << 20);
  EPI_SETUP
#pragma unroll
  for (int ti = 0; ti < 2; ++ti)
#pragma unroll
    for (int tj = 0; tj < 2; ++tj)
#pragma unroll
      for (int r = 0; r < 4; ++r) {
        int row = m0 + wm + ti * 16 + lq4 + r;
        int col = n0 + wn + tj * 16 + lr;
        Cb[(long long)row * 1024 + col] = f2bf(acc[ti][tj][r]);
      }
}

// ---- wave-level reductions (no barriers) -----------------------------------
__device__ __forceinline__ float wred_sum(float v) {
#pragma unroll
  for (int m = 32; m > 0; m >>= 1) v += __shfl_xor(v, m, 64);
  return v;
}
__device__ __forceinline__ void wred_sum2(float& a, float& b) {
#pragma unroll
  for (int m = 32; m > 0; m >>= 1) {
    float ta = __shfl_xor(a, m, 64);
    float tb = __shfl_xor(b, m, 64);
    a += ta; b += tb;
  }
}
__device__ __forceinline__ float wred_max(float v) {
#pragma unroll
  for (int m = 32; m > 0; m >>= 1) v = fmaxf(v, __shfl_xor(v, m, 64));
  return v;
}

// ---- z-score attention: one wave per row, all 4 heads ----------------------
__global__ __launch_bounds__(256) void zscore_w(
    const u16* __restrict__ sc, const int* __restrict__ adj,
    const int* __restrict__ mask, u16* __restrict__ wout,
    float* __restrict__ denh) {
  int wv = threadIdx.x >> 6, lane = threadIdx.x & 63;
  int row = (blockIdx.x << 2) + wv;
  int b = row >> 10, n = row & 1023;
  int e0 = lane << 4;
  const int* arow = adj + ((long long)row << 10) + e0;
  const int* mrow = mask + (b << 10) + e0;

  unsigned int vbits = 0, abits = 0;
#pragma unroll
  for (int q = 0; q < 4; ++q) {
    int4 a4 = *reinterpret_cast<const int4*>(arow + (q << 2));
    int4 m4 = *reinterpret_cast<const int4*>(mrow + (q << 2));
    vbits |= (unsigned)(m4.x == 0) << (q * 4);
    vbits |= (unsigned)(m4.y == 0) << (q * 4 + 1);
    vbits |= (unsigned)(m4.z == 0) << (q * 4 + 2);
    vbits |= (unsigned)(m4.w == 0) << (q * 4 + 3);
    abits |= (unsigned)(a4.x != 0) << (q * 4);
    abits |= (unsigned)(a4.y != 0) << (q * 4 + 1);
    abits |= (unsigned)(a4.z != 0) << (q * 4 + 2);
    abits |= (unsigned)(a4.w != 0) << (q * 4 + 3);
  }
  float cnt = wred_sum((float)__popc(vbits));
  float cnteff = cnt + 0.0001f;

  for (int h = 0; h < 4; ++h) {
    int z = (h << 2) + b;
    const u16* srow = sc + ((long long)z << 20) + ((long long)n << 10) + e0;
    float s[16];
#pragma unroll
    for (int q = 0; q < 2; ++q) {
      uint4 u = *reinterpret_cast<const uint4*>(srow + (q << 3));
      unsigned int uu[4] = {u.x, u.y, u.z, u.w};
#pragma unroll
      for (int t = 0; t < 4; ++t) {
        union { unsigned int i; float f; } lo, hi;
        lo.i = uu[t] << 16;
        hi.i = uu[t] & 0xffff0000u;
        s[q * 8 + t * 2] = lo.f;
        s[q * 8 + t * 2 + 1] = hi.f;
      }
    }
    float suml = 0.f, sql = 0.f;
#pragma unroll
    for (int u = 0; u < 16; ++u)
      if ((vbits >> u) & 1) { suml += s[u]; sql += s[u] * s[u]; }
    wred_sum2(suml, sql);
    float mean = suml / cnteff;
    float sdata = sql - 2.f * mean * suml + cnt * mean * mean;
    float stdv = sqrtf(fmaxf(sdata, 0.f) / cnteff + 1e-10f);
    float inv = 1.f / (stdv + 0.0001f);

    float maxl = -1e9f;
#pragma unroll
    for (int u = 0; u < 16; ++u) {
      float zz = (s[u] - mean) * inv;
      int vv = (vbits >> u) & 1;
      zz = vv ? zz : 0.f;
      s[u] = zz;
      if (vv && zz >= 0.f) maxl = fmaxf(maxl, zz);
    }
    float rowmax = wred_max(maxl);

    float e[16], el = 0.f;
#pragma unroll
    for (int u = 0; u < 16; ++u) {
      int vv = (vbits >> u) & 1, aa = (abits >> u) & 1;
      float ev = (vv && aa && (s[u] >= 0.f)) ? expf(s[u] - rowmax) : 0.f;
      e[u] = ev + 1e-10f;
      el += e[u];
    }
    float esum = wred_sum(el);
    float rinv = 1.f / esum;

    float wl = 0.f;
    unsigned int wo[8];
#pragma unroll
    for (int u = 0; u < 16; u += 2) {
      int s0 = ((vbits >> u) & 1) && ((abits >> u) & 1) && (s[u] >= 0.f);
      int s1 = ((vbits >> (u + 1)) & 1) && ((abits >> (u + 1)) & 1) && (s[u + 1] >= 0.f);
      float w0 = s0 ? e[u] * rinv : 0.f;
      float w1 = s1 ? e[u + 1] * rinv : 0.f;
      wl += w0 + w1;
      wo[u >> 1] = (unsigned)f2bf(w0) | ((unsigned)f2bf(w1) << 16);
    }
    float wsum = wred_sum(wl);

    u16* orow = wout + ((size_t)z << 20) + ((size_t)n << 10) + e0;
    reinterpret_cast<uint4*>(orow)[0] = make_uint4(wo[0], wo[1], wo[2], wo[3]);
    reinterpret_cast<uint4*>(orow)[1] = make_uint4(wo[4], wo[5], wo[6], wo[7]);
    if (lane == 0) denh[(z << 10) + n] = wsum + 1.0f;
  }
}

// ---- fused GCN layer: 512 threads (8 waves = 2/SIMD), dbuf both stages -----
__global__ __launch_bounds__(512) void gcn_k(
    const u16* __restrict__ wght, const u16* __restrict__ srcT, int zmaskB,
    const u16* __restrict__ addsrc, int ldadd, long long sAdd, int hmul,
    const u16* __restrict__ WgT_all, const float* __restrict__ bg_all,
    const float* __restrict__ den, int l,
    u16* __restrict__ obT, u16* __restrict__ fin) {
  __shared__ u16 lds[53760];  // 107.5 KB
  u16* As0 = lds;             // [64][72]
  u16* As1 = lds + 4608;
  u16* Bs0 = lds + 9216;      // [256][72]
  u16* Bs1 = lds + 27648;
  u16* Ts = lds;              // [64][264] (stage 2, overlays stage-1 A/B0)
  u16* Ws0 = lds + 16896;     // [256][72]
  u16* Ws1 = lds + 35328;
  int tid = threadIdx.x;
  int m0 = blockIdx.x << 6;
  int z = blockIdx.y;
  int lane = tid & 63, w = tid >> 6;
  int wm = (w & 1) << 5, wn = (w >> 1) << 6;
  int lr = lane & 15, lq8 = (lane >> 4) << 3, lq4 = (lane >> 4) << 2;

  const u16* Aw = wght + ((long long)z << 20) + (long long)m0 * 1024;
  const u16* Bt = srcT + (long long)(z & zmaskB) * 262144;
  const u16* addb = addsrc + (long long)(z & 3) * sAdd + (z >> 2) * hmul;
  int idx2 = (z >> 2) * 2 + l;
  const u16* Wg = WgT_all + (long long)idx2 * 65536;

  floatx4 acc[2][4] = {};
  int rA = tid >> 3, cA = (tid & 7) << 3;
  int rowB[4], colB[4];
#pragma unroll
  for (int j = 0; j < 4; ++j) {
    int id = tid + (j << 9);
    rowB[j] = id >> 3; colB[j] = (id & 7) << 3;
  }

  float4 pa, pb[4];
  pa = *reinterpret_cast<const float4*>(Aw + (long long)rA * 1024 + cA);
#pragma unroll
  for (int j = 0; j < 4; ++j)
    pb[j] = *reinterpret_cast<const float4*>(Bt + (long long)rowB[j] * 1024 + colB[j]);
  *reinterpret_cast<float4*>(As0 + rA * 72 + cA) = pa;
#pragma unroll
  for (int j = 0; j < 4; ++j)
    *reinterpret_cast<float4*>(Bs0 + rowB[j] * 72 + colB[j]) = pb[j];
  __syncthreads();

  // ---- stage 1: K=1024, 16 slabs ----
  for (int s = 0; s < 16; ++s) {
    const u16* Ac = (s & 1) ? As1 : As0;
    const u16* Bc = (s & 1) ? Bs1 : Bs0;
    if (s < 15) {
      int off = (s + 1) << 6;
      pa = *reinterpret_cast<const float4*>(Aw + (long long)rA * 1024 + off + cA);
#pragma unroll
      for (int j = 0; j < 4; ++j)
        pb[j] = *reinterpret_cast<const float4*>(Bt + (long long)rowB[j] * 1024 + off + colB[j]);
    }
#pragma unroll
    for (int kc = 0; kc < 64; kc += 32) {
      short8 a[2], b[4];
#pragma unroll
      for (int t = 0; t < 2; ++t)
        a[t] = *reinterpret_cast<const short8*>(Ac + (wm + t * 16 + lr) * 72 + kc + lq8);
#pragma unroll
      for (int t = 0; t < 4; ++t)
        b[t] = *reinterpret_cast<const short8*>(Bc + (wn + t * 16 + lr) * 72 + kc + lq8);
#pragma unroll
      for (int ti = 0; ti < 2; ++ti)
#pragma unroll
        for (int tj = 0; tj < 4; ++tj)
          acc[ti][tj] =
              __builtin_amdgcn_mfma_f32_16x16x32_bf16(a[ti], b[tj], acc[ti][tj], 0, 0, 0);
    }
    if (s < 15) {
      u16* An = (s & 1) ? As0 : As1;
      u16* Bn = (s & 1) ? Bs0 : Bs1;
      *reinterpret_cast<float4*>(An + rA * 72 + cA) = pa;
#pragma unroll
      for (int j = 0; j < 4; ++j)
        *reinterpret_cast<float4*>(Bn + rowB[j] * 72 + colB[j]) = pb[j];
    }
    __syncthreads();
  }

  // ---- T (+addsrc) -> Ts in A-operand layout; zero accs ----
#pragma unroll
  for (int ti = 0; ti < 2; ++ti)
#pragma unroll
    for (int tj = 0; tj < 4; ++tj)
#pragma unroll
      for (int r = 0; r < 4; ++r) {
        int row = wm + ti * 16 + lq4 + r;
        int col = wn + tj * 16 + lr;
        float v = acc[ti][tj][r] + bf2f(addb[(long long)(m0 + row) * ldadd + col]);
        Ts[row * 264 + col] = f2bf(v);
        acc[ti][tj][r] = 0.f;
      }
  float4 pw[4];
#pragma unroll
  for (int j = 0; j < 4; ++j)
    pw[j] = *reinterpret_cast<const float4*>(Wg + (long long)rowB[j] * 256 + colB[j]);
#pragma unroll
  for (int j = 0; j < 4; ++j)
    *reinterpret_cast<float4*>(Ws0 + rowB[j] * 72 + colB[j]) = pw[j];
  __syncthreads();

  // ---- stage 2: out = T @ Wg^T, K=256, 4 slabs ----
  for (int s = 0; s < 4; ++s) {
    const u16* Wc = (s & 1) ? Ws1 : Ws0;
    int kc0 = s << 6;
    if (s < 3) {
      int off = (s + 1) << 6;
#pragma unroll
      for (int j = 0; j < 4; ++j)
        pw[j] = *reinterpret_cast<const float4*>(Wg + (long long)rowB[j] * 256 + off + colB[j]);
    }
#pragma unroll
    for (int kc = 0; kc < 64; kc += 32) {
      short8 a[2], b[4];
#pragma unroll
      for (int t = 0; t < 2; ++t)
        a[t] = *reinterpret_cast<const short8*>(Ts + (wm + t * 16 + lr) * 264 + kc0 + kc + lq8);
#pragma unroll
      for (int t = 0; t < 4; ++t)
        b[t] = *reinterpret_cast<const short8*>(Wc + (wn + t * 16 + lr) * 72 + kc + lq8);
#pragma unroll
      for (int ti = 0; ti < 2; ++ti)
#pragma unroll
        for (int tj = 0; tj < 4; ++tj)
          acc[ti][tj] =
              __builtin_amdgcn_mfma_f32_16x16x32_bf16(a[ti], b[tj], acc[ti][tj], 0, 0, 0);
    }
    if (s < 3) {
      u16* Wn = (s & 1) ? Ws0 : Ws1;
#pragma unroll
      for (int j = 0; j < 4; ++j)
        *reinterpret_cast<float4*>(Wn + rowB[j] * 72 + colB[j]) = pw[j];
    }
    __syncthreads();
  }

  // ---- epilogue ----
  const float* bb = bg_all + idx2 * 256;
  const float* dn = den + (z << 10);
  long long finbase = (long long)(z & 3) * 2097152 + idx2 * 256;
#pragma unroll
  for (int ti = 0; ti < 2; ++ti) {
    int row = m0 + wm + ti * 16 + lq4;
#pragma unroll
    for (int tj = 0; tj < 4; ++tj) {
      int col = wn + tj * 16 + lr;
      u16 bv4[4];
#pragma unroll
      for (int r = 0; r < 4; ++r) {
        float v = (acc[ti][tj][r] + 2.f * bb[col]) / dn[row + r];
        v = fmaxf(v, 0.f);
        bv4[r] = f2bf(v);
        fin[finbase + (long long)(row + r) * 2048 + col] = bv4[r];
      }
      if (obT) {
        ushort4 t4 = {bv4[0], bv4[1], bv4[2], bv4[3]};
        *reinterpret_cast<ushort4*>(obT + ((long long)z << 18) +
                                    (long long)col * 1024 + row) = t4;
      }
    }
  }
}

// ---- final: out = X + b_out + fin @ Wo^T  (512 thr, full K, no atomics) ----
__global__ __launch_bounds__(512) void mfinal_k(
    const u16* __restrict__ fin, const u16* __restrict__ WoT,
    const float* __restrict__ X, const float* __restrict__ bias,
    float* __restrict__ out) {
  __shared__ u16 lds[36864];  // 2 bufs A + 2 bufs B, each 64*72
  u16* As0 = lds;
  u16* As1 = lds + 4608;
  u16* Bs0 = lds + 9216;
  u16* Bs1 = lds + 13824;
  int tid = threadIdx.x;
  int m0 = blockIdx.y << 6, n0 = blockIdx.x << 6;
  int lane = tid & 63, w = tid >> 6;
  int wm = (w & 3) << 4, wn = (w >> 2) << 5;  // wave tile 16x32
  int lr = lane & 15, lq8 = (lane >> 4) << 3, lq4 = (lane >> 4) << 2;

  const u16* Ab = fin + (long long)m0 * 2048;
  const u16* Bb = WoT + (long long)n0 * 2048;
  int r0 = tid >> 3, c8 = (tid & 7) << 3;  // 64 rows x 8 col-groups = 512 thr

  floatx4 acc[2] = {};
  float4 pa = *reinterpret_cast<const float4*>(Ab + (long long)r0 * 2048 + c8);
  float4 pb = *reinterpret_cast<const float4*>(Bb + (long long)r0 * 2048 + c8);
  *reinterpret_cast<float4*>(As0 + r0 * 72 + c8) = pa;
  *reinterpret_cast<float4*>(Bs0 + r0 * 72 + c8) = pb;
  __syncthreads();

  for (int s = 0; s < 32; ++s) {
    const u16* Ac = (s & 1) ? As1 : As0;
    const u16* Bc = (s & 1) ? Bs1 : Bs0;
    if (s < 31) {
      int off = (s + 1) << 6;
      pa = *reinterpret_cast<const float4*>(Ab + (long long)r0 * 2048 + off + c8);
      pb = *reinterpret_cast<const float4*>(Bb + (long long)r0 * 2048 + off + c8);
    }
#pragma unroll
    for (int kc = 0; kc < 64; kc += 32) {
      short8 a = *reinterpret_cast<const short8*>(Ac + (wm + lr) * 72 + kc + lq8);
      short8 b0 = *reinterpret_cast<const short8*>(Bc + (wn + lr) * 72 + kc + lq8);
      short8 b1 = *reinterpret_cast<const short8*>(Bc + (wn + 16 + lr) * 72 + kc + lq8);
      acc[0] = __builtin_amdgcn_mfma_f32_16x16x32_bf16(a, b0, acc[0], 0, 0, 0);
      acc[1] = __builtin_amdgcn_mfma_f32_16x16x32_bf16(a, b1, acc[1], 0, 0, 0);
    }
    if (s < 31) {
      u16* An = (s & 1) ? As0 : As1;
      u16* Bn = (s & 1) ? Bs0 : Bs1;
      *reinterpret_cast<float4*>(An + r0 * 72 + c8) = pa;
      *reinterpret_cast<float4*>(Bn + r0 * 72 + c8) = pb;
    }
    __syncthreads();
  }

#pragma unroll
  for (int tj = 0; tj < 2; ++tj)
#pragma unroll
    for (int r = 0; r < 4; ++r) {
      int row = m0 + wm + lq4 + r;
      int col = n0 + wn + tj * 16 + lr;
      out[(long long)row * 256 + col] =
          acc[tj][r] + bias[col] + X[(long long)row * 256 + col];
    }
}

// ---- prep: LDS-tiled transposes + concat (one launch) ----------------------
__global__ __launch_bounds__(256) void prep_k(
    const float* __restrict__ X, const float* __restrict__ R,
    const float* __restrict__ W_Q, const float* __restrict__ W_K,
    const float* __restrict__ W_gcn, const float* __restrict__ W_out,
    u16* __restrict__ A, u16* __restrict__ XT, u16* __restrict__ WQT,
    u16* __restrict__ WKT, u16* __restrict__ WgT, u16* __restrict__ WoT) {
  int bi = blockIdx.x;
  int tid = threadIdx.x;
  if (bi < 560) {
    __shared__ u16 tile[64 * LDS_P];
    const float* S;
    u16* D;
    int I, ti, tj;
    if (bi < 256) {  // XT: [4] 1024x256 -> 256x1024
      int zz = bi >> 6, rem = bi & 63;
      ti = rem >> 2; tj = rem & 3; I = 1024;
      S = X + zz * 262144; D = XT + zz * 262144;
    } else if (bi < 288) {  // WQT: 512x256 -> 256x512
      int t = bi - 256; ti = t >> 2; tj = t & 3; I = 512;
      S = W_Q; D = WQT;
    } else if (bi < 304) {  // WKT
      int t = bi - 288; ti = t >> 2; tj = t & 3; I = 256;
      S = W_K; D = WKT;
    } else if (bi < 432) {  // WgT: [8] 256x256
      int t = bi - 304; int zz = t >> 4, rem = t & 15;
      ti = rem >> 2; tj = rem & 3; I = 256;
      S = W_gcn + zz * 65536; D = WgT + zz * 65536;
    } else {  // WoT: 2048x256 -> 256x2048
      int t = bi - 432; ti = t >> 2; tj = t & 3; I = 2048;
      S = W_out; D = WoT;
    }
    int rr = tid >> 4, cc = (tid & 15) << 2;
#pragma unroll
    for (int q = 0; q < 4; ++q) {
      int r = rr + (q << 4);
      float4 v = *reinterpret_cast<const float4*>(S + (long long)(ti * 64 + r) * 256 +
                                                  tj * 64 + cc);
      ushort4 h = {f2bf(v.x), f2bf(v.y), f2bf(v.z), f2bf(v.w)};
      *reinterpret_cast<ushort4*>(tile + r * LDS_P + cc) = h;
    }
    __syncthreads();
    int jl = tid >> 2, il = (tid & 3) << 4;
    u16 vals[16];
#pragma unroll
    for (int u = 0; u < 16; ++u) vals[u] = tile[(il + u) * LDS_P + jl];
    u16* dp = D + (long long)(tj * 64 + jl) * I + ti * 64 + il;
    reinterpret_cast<uint4*>(dp)[0] = *reinterpret_cast<uint4*>(vals);
    reinterpret_cast<uint4*>(dp)[1] = *reinterpret_cast<uint4*>(vals + 8);
  } else {  // concat A = [X|R] bf16
    int gid = (bi - 560) * 256 + tid;
    int col = gid & 511, row = gid >> 9;
    float v = (col < 256) ? X[row * 256 + col] : R[row * 256 + col - 256];
    A[gid] = f2bf(v);
  }
}

// ---- launch ----------------------------------------------------------------
extern "C" void kernel_launch(void* const* d_in, const int* in_sizes, int n_in,
                              void* d_out, int out_size, void* d_ws, size_t ws_size,
                              hipStream_t stream) {
  const float* X = (const float*)d_in[0];
  const float* R = (const float*)d_in[1];
  const int* adj = (const int*)d_in[2];
  const int* mask = (const int*)d_in[3];
  const float* W_Q = (const float*)d_in[4];
  const float* b_Q = (const float*)d_in[5];
  const float* W_K = (const float*)d_in[6];
  const float* b_K = (const float*)d_in[7];
  const float* W_gcn = (const float*)d_in[8];
  const float* b_gcn = (const float*)d_in[9];
  const float* W_out = (const float*)d_in[10];
  const float* b_out = (const float*)d_in[11];
  float* out = (float*)d_out;

  u16* wsu = (u16*)d_ws;
  u16* A_qk = wsu;                        // [4096][512]      2M u16
  u16* qbf  = A_qk + (2u << 20);          // [4096][256]      1M
  u16* kbf  = qbf + (1u << 20);           // [4096][256]      1M
  u16* XT   = kbf + (1u << 20);           // [4][256][1024]   1M
  u16* WQT  = XT + (1u << 20);            // [256][512]       128K
  u16* WKT  = WQT + (1u << 17);           // [256][256]       64K
  u16* WgT  = WKT + (1u << 16);           // [8][256][256]    512K
  u16* WoT  = WgT + (1u << 19);           // [256][2048]      512K
  u16* obT  = WoT + (1u << 19);           // [16][256][1024]  4M
  u16* finb = obT + (4u << 20);           // [4][1024][2048]  8M
  u16* wght = finb + (8u << 20);          // [16][1024][1024] 16M
  float* den = (float*)(wght + (16u << 20));   // [16][1024] f32
  u16* sc = (u16*)(den + (1 << 14));           // [16][1024][1024] bf16 (32 MB)

  // prep: tiled transposes + concat
  prep_k<<<8752, 256, 0, stream>>>(X, R, W_Q, W_K, W_gcn, W_out,
                                   A_qk, XT, WQT, WKT, WgT, WoT);

  // q & k projections
  proj2_k<<<dim3(4, 64, 2), 256, 0, stream>>>(A_qk, WQT, WKT, b_Q, b_K, qbf, kbf);

  // scores (bf16) + z-score chain (wave-per-row)
  mscore_k<<<dim3(16, 16, 16), 256, 0, stream>>>(qbf, kbf, sc);
  zscore_w<<<1024, 256, 0, stream>>>(sc, adj, mask, wght, den);

  // fused GCN layers (512 threads = 2 waves/SIMD); layer 1 reads +src from finb
  gcn_k<<<dim3(16, 16), 512, 0, stream>>>(wght, XT, 3, A_qk, 512, 524288LL, 0,
                                          WgT, b_gcn, den, 0, obT, finb);
  gcn_k<<<dim3(16, 16), 512, 0, stream>>>(wght, obT, 15, finb, 2048, 2097152LL, 512,
                                          WgT, b_gcn, den, 1, nullptr, finb);

  // final projection + residual (512 threads, full K, no atomics)
  mfinal_k<<<dim3(4, 64), 512, 0, stream>>>(finb, WoT, X, b_out, out);
}